// Round 21
// baseline (73.499 us; speedup 1.0000x reference)
//
#include <hip/hip_runtime.h>

constexpr int HH = 100;
constexpr int WW = 100;
constexpr int NH = 8;
constexpr int NP = 4;
constexpr int B  = 4;
constexpr int Q  = HH * WW;   // 10000
constexpr int S  = Q;
constexpr int K  = 256;
constexpr int DH = 32;
constexpr int M  = B * Q;     // 40000
constexpr int NTILES = M / 32; // 1250 (out_proj)
constexpr int T64 = M / 64;    // 625 (stage1 64-row tiles)

typedef __attribute__((ext_vector_type(8))) short short8;
typedef __attribute__((ext_vector_type(4))) float f32x4;

struct __align__(8) ushort4p { unsigned short x, y, z, w; };

__device__ inline unsigned short f2bf(float f) {
    unsigned u = __builtin_bit_cast(unsigned, f);
    u += 0x7fffu + ((u >> 16) & 1u);          // RNE
    return (unsigned short)(u >> 16);
}
__device__ inline float bf2f(unsigned short h) {
    return __builtin_bit_cast(float, ((unsigned)h) << 16);
}
__device__ inline unsigned short f2h(float f) {
    _Float16 h = (_Float16)f;
    return __builtin_bit_cast(unsigned short, h);
}
__device__ inline float h2f(unsigned short u) {
    return (float)__builtin_bit_cast(_Float16, u);
}

// Non-draining barrier: waits LDS ops only; global stores/loads stay in flight.
__device__ inline void softbar() {
    asm volatile("s_waitcnt lgkmcnt(0)" ::: "memory");
    __builtin_amdgcn_s_barrier();
}

// LDS bf16 tile helpers (16B-chunk XOR swizzle: chunk ^= row&7).
__device__ inline void lds_st16s(short* base, int row, int stride, int kcol, short8 v) {
    *reinterpret_cast<short8*>(&base[row * stride + (kcol ^ ((row & 7) << 3))]) = v;
}
__device__ inline short8 lds_ld16s(const short* base, int row, int stride, int kcol) {
    return *reinterpret_cast<const short8*>(&base[row * stride + (kcol ^ ((row & 7) << 3))]);
}

__device__ inline short8 cvt8(float4 a, float4 b) {
    short8 r;
    r[0] = (short)f2bf(a.x); r[1] = (short)f2bf(a.y);
    r[2] = (short)f2bf(a.z); r[3] = (short)f2bf(a.w);
    r[4] = (short)f2bf(b.x); r[5] = (short)f2bf(b.y);
    r[6] = (short)f2bf(b.z); r[7] = (short)f2bf(b.w);
    return r;
}

// ---------------------------------------------------------------------------
// Stage 1 (R20 structure, 64-ROW TILES): value proj + off/attn proj.
// 256 blocks x 1024 thr, B in VGPRs, A dbuf in LDS (2 x 32 KB), 1-deep
// prefetch, softbar per tile, swapped-MFMA packed stores. 64-row tiles
// double per-tile MFMA work (32/wave) to amortize per-tile fixed cost.
//   blocks 0..142   : enc @ W_val^T   -> vflat bf16
//   blocks 143..255 : hidden @ [W_off;W_attn]^T -> proj f16 [M][96]
// ---------------------------------------------------------------------------
__global__ __launch_bounds__(1024) void stage1(
    const float* __restrict__ enc, const float* __restrict__ Wval,
    const float* __restrict__ bval, unsigned short* __restrict__ vflat,
    const float* __restrict__ hidden, const float* __restrict__ Woff,
    const float* __restrict__ Wattn, const float* __restrict__ boff,
    const float* __restrict__ battn, unsigned short* __restrict__ proj)
{
    __shared__ __align__(16) short As[2][64 * 256];   // 2 x 32 KB

    const int tid  = threadIdx.x;
    const int lane = tid & 63, w = tid >> 6;
    const int l15  = lane & 15, l4 = lane >> 4;
    const int arow = tid >> 4;            // 0..63
    const int ak   = (tid & 15) * 16;     // 16 f32 per thread per row

    constexpr int NV = 143, NJ = 113;

    if (blockIdx.x < NV) {
        // ---------------- value projection ----------------
        const int n = w * 16 + l15;          // lane's weight row
        short8 breg[8];
#pragma unroll
        for (int ks = 0; ks < 8; ++ks) {
            const float* s = &Wval[(size_t)n * K + ks * 32 + l4 * 8];
            breg[ks] = cvt8(*reinterpret_cast<const float4*>(s),
                            *reinterpret_cast<const float4*>(s + 4));
        }
        const int nbase = w * 16 + l4 * 4;
        const float4 bias4 = *reinterpret_cast<const float4*>(&bval[nbase]);
        const int h = w >> 1;                // nbase>>5, uniform per wave
        const int dd0 = nbase & 31;

        int t = blockIdx.x;
        float4 f0, f1, f2, f3;
        auto lda = [&](int tt) {
            const float* s = &enc[(size_t)(tt * 64 + arow) * K + ak];
            f0 = *reinterpret_cast<const float4*>(s);
            f1 = *reinterpret_cast<const float4*>(s + 4);
            f2 = *reinterpret_cast<const float4*>(s + 8);
            f3 = *reinterpret_cast<const float4*>(s + 12);
        };
        auto wr = [&](short* dst) {
            lds_st16s(dst, arow, 256, ak, cvt8(f0, f1));
            lds_st16s(dst, arow, 256, ak + 8, cvt8(f2, f3));
        };
        lda(t);
        wr(As[0]);
        __syncthreads();
        int cur = 0;
        for (; t < T64; t += NV) {
            const bool more = (t + NV < T64);
            if (more) lda(t + NV);            // overlaps MFMA below

            f32x4 acc[4];
#pragma unroll
            for (int mf = 0; mf < 4; ++mf) acc[mf] = f32x4{0.f, 0.f, 0.f, 0.f};
#pragma unroll
            for (int ks = 0; ks < 8; ++ks) {
                const int kc = ks * 32 + l4 * 8;
#pragma unroll
                for (int mf = 0; mf < 4; ++mf) {
                    const short8 a = lds_ld16s(As[cur], mf * 16 + l15, 256, kc);
                    acc[mf] = __builtin_amdgcn_mfma_f32_16x16x32_bf16(breg[ks], a, acc[mf], 0, 0, 0);
                }
            }
#pragma unroll
            for (int mf = 0; mf < 4; ++mf) {
                const int m = t * 64 + mf * 16 + l15;
                const int b_ = m / S, s_ = m - b_ * S;
                ushort4p pk;
                pk.x = f2bf(acc[mf][0] + bias4.x);
                pk.y = f2bf(acc[mf][1] + bias4.y);
                pk.z = f2bf(acc[mf][2] + bias4.z);
                pk.w = f2bf(acc[mf][3] + bias4.w);
                *reinterpret_cast<ushort4p*>(
                    &vflat[(((size_t)(b_ * NH + h)) * S + s_) * DH + dd0]) = pk;
            }
            if (more) wr(As[cur ^ 1]);
            softbar();
            cur ^= 1;
        }
    } else {
        // ---------------- off+attn projection ----------------
        // waves 0..11: nf = w>>1 (16 cols), mh = w&1 (32-row half -> 2 m-frags)
        const int nf = w >> 1, mh = w & 1;
        const int n = nf * 16 + l15;
        short8 breg[8];
        float4 bias4 = {0.f, 0.f, 0.f, 0.f};
        const int nbase = nf * 16 + l4 * 4;
        if (w < 12) {
#pragma unroll
            for (int ks = 0; ks < 8; ++ks) {
                const float* s = (n < 64)
                    ? &Woff[(size_t)n * K + ks * 32 + l4 * 8]
                    : &Wattn[(size_t)(n - 64) * K + ks * 32 + l4 * 8];
                breg[ks] = cvt8(*reinterpret_cast<const float4*>(s),
                                *reinterpret_cast<const float4*>(s + 4));
            }
            bias4 = (nf < 4)
                ? *reinterpret_cast<const float4*>(&boff[nbase])
                : *reinterpret_cast<const float4*>(&battn[nbase - 64]);
        }

        int t = blockIdx.x - NV;
        float4 f0, f1, f2, f3;
        auto lda = [&](int tt) {
            const float* s = &hidden[(size_t)(tt * 64 + arow) * K + ak];
            f0 = *reinterpret_cast<const float4*>(s);
            f1 = *reinterpret_cast<const float4*>(s + 4);
            f2 = *reinterpret_cast<const float4*>(s + 8);
            f3 = *reinterpret_cast<const float4*>(s + 12);
        };
        auto wr = [&](short* dst) {
            lds_st16s(dst, arow, 256, ak, cvt8(f0, f1));
            lds_st16s(dst, arow, 256, ak + 8, cvt8(f2, f3));
        };
        lda(t);
        wr(As[0]);
        __syncthreads();
        int cur = 0;
        for (; t < T64; t += NJ) {
            const bool more = (t + NJ < T64);
            if (more) lda(t + NJ);

            if (w < 12) {
                f32x4 acc0 = {0.f, 0.f, 0.f, 0.f}, acc1 = {0.f, 0.f, 0.f, 0.f};
#pragma unroll
                for (int ks = 0; ks < 8; ++ks) {
                    const int kc = ks * 32 + l4 * 8;
                    const short8 a0 = lds_ld16s(As[cur], mh * 32 + l15, 256, kc);
                    const short8 a1 = lds_ld16s(As[cur], mh * 32 + 16 + l15, 256, kc);
                    acc0 = __builtin_amdgcn_mfma_f32_16x16x32_bf16(breg[ks], a0, acc0, 0, 0, 0);
                    acc1 = __builtin_amdgcn_mfma_f32_16x16x32_bf16(breg[ks], a1, acc1, 0, 0, 0);
                }
                {
                    const int m = t * 64 + mh * 32 + l15;
                    ushort4p pk;
                    pk.x = f2h(acc0[0] + bias4.x);
                    pk.y = f2h(acc0[1] + bias4.y);
                    pk.z = f2h(acc0[2] + bias4.z);
                    pk.w = f2h(acc0[3] + bias4.w);
                    *reinterpret_cast<ushort4p*>(&proj[(size_t)m * 96 + nbase]) = pk;
                }
                {
                    const int m = t * 64 + mh * 32 + 16 + l15;
                    ushort4p pk;
                    pk.x = f2h(acc1[0] + bias4.x);
                    pk.y = f2h(acc1[1] + bias4.y);
                    pk.z = f2h(acc1[2] + bias4.z);
                    pk.w = f2h(acc1[3] + bias4.w);
                    *reinterpret_cast<ushort4p*>(&proj[(size_t)m * 96 + nbase]) = pk;
                }
            }
            if (more) wr(As[cur ^ 1]);
            softbar();
            cur ^= 1;
        }
    }
}

// ---------------------------------------------------------------------------
// Kernel S: bilinear sampling + attention aggregation (R14/R20 exact).
// 4 lanes per (b,h,q) group; lane owns 8 d-elements (16B gathers).
// 64 groups per 256-thread block; 5000 blocks, XCD-swizzled.
// ---------------------------------------------------------------------------
__global__ __launch_bounds__(256) void sample_agg(
    const unsigned short* __restrict__ vflat,  // [B*NH][S][DH] bf16
    const unsigned short* __restrict__ proj,   // [M][96] f16
    const float* __restrict__ ref,             // [M][2]
    unsigned short* __restrict__ tmp)          // [M][256] bf16
{
    const int nblk = gridDim.x;                // 5000, %8 == 0
    const int cpx  = nblk >> 3;
    const int swz  = (blockIdx.x & 7) * cpx + (blockIdx.x >> 3);

    const int lg   = threadIdx.x >> 2;   // 0..63
    const int lane = threadIdx.x & 3;
    const int d0   = lane * 8;

    const int g  = swz * 64 + lg;
    const int q  = g % Q;
    const int bh = g / Q;
    const int b  = bh >> 3;
    const int h  = bh & 7;

    const size_t bq = (size_t)b * Q + q;
    const float refx = ref[bq * 2 + 0];
    const float refy = ref[bq * 2 + 1];
    const unsigned short* pr = proj + bq * 96;

    float l[NP];
#pragma unroll
    for (int p = 0; p < NP; ++p) l[p] = h2f(pr[64 + h * 4 + p]);
    const float mx = fmaxf(fmaxf(l[0], l[1]), fmaxf(l[2], l[3]));
    float e[NP];
    float esum = 0.f;
#pragma unroll
    for (int p = 0; p < NP; ++p) { e[p] = __expf(l[p] - mx); esum += e[p]; }
    const float inv = 1.f / esum;

    const unsigned short* vbase = vflat + (size_t)bh * (S * DH);

    int   cidx[NP][4];
    float cw[NP][4];
#pragma unroll
    for (int p = 0; p < NP; ++p) {
        const float ox = h2f(pr[h * 8 + p * 2 + 0]);
        const float oy = h2f(pr[h * 8 + p * 2 + 1]);
        const float x = fmaf(refx, (float)WW, ox) - 0.5f;
        const float y = fmaf(refy, (float)HH, oy) - 0.5f;
        const float x0f = floorf(x), y0f = floorf(y);
        const float wx1 = x - x0f, wx0 = 1.f - wx1;
        const float wy1 = y - y0f, wy0 = 1.f - wy1;
        const int x0 = (int)x0f, y0 = (int)y0f;
        const bool vx0 = (x0 >= 0) && (x0 < WW);
        const bool vx1 = (x0 + 1 >= 0) && (x0 + 1 < WW);
        const bool vy0 = (y0 >= 0) && (y0 < HH);
        const bool vy1 = (y0 + 1 >= 0) && (y0 + 1 < HH);
        const int xi0 = min(max(x0, 0), WW - 1);
        const int xi1 = min(max(x0 + 1, 0), WW - 1);
        const int yi0 = min(max(y0, 0), HH - 1);
        const int yi1 = min(max(y0 + 1, 0), HH - 1);
        const float ap = e[p] * inv;
        cw[p][0] = ap * wx0 * wy0 * ((vx0 && vy0) ? 1.f : 0.f);
        cw[p][1] = ap * wx1 * wy0 * ((vx1 && vy0) ? 1.f : 0.f);
        cw[p][2] = ap * wx0 * wy1 * ((vx0 && vy1) ? 1.f : 0.f);
        cw[p][3] = ap * wx1 * wy1 * ((vx1 && vy1) ? 1.f : 0.f);
        cidx[p][0] = (yi0 * WW + xi0) * DH + d0;
        cidx[p][1] = (yi0 * WW + xi1) * DH + d0;
        cidx[p][2] = (yi1 * WW + xi0) * DH + d0;
        cidx[p][3] = (yi1 * WW + xi1) * DH + d0;
    }

    float o[8];
#pragma unroll
    for (int j = 0; j < 8; ++j) o[j] = 0.f;
#pragma unroll
    for (int p = 0; p < NP; ++p) {
#pragma unroll
        for (int c = 0; c < 4; ++c) {
            const short8 v = *reinterpret_cast<const short8*>(&vbase[cidx[p][c]]);
            const float wgt = cw[p][c];
#pragma unroll
            for (int j = 0; j < 8; ++j)
                o[j] = fmaf(wgt, bf2f((unsigned short)v[j]), o[j]);
        }
    }

    short8 ov;
#pragma unroll
    for (int j = 0; j < 8; ++j) ov[j] = (short)f2bf(o[j]);
    *reinterpret_cast<short8*>(&tmp[bq * 256 + h * 32 + d0]) = ov;
}

// ---------------------------------------------------------------------------
// Kernel O: out projection (R20 exact): 256 blocks x 1024 thr,
// W in VGPRs, A dbuf in LDS, 1-deep prefetch, softbar, packed f32x4 stores.
// ---------------------------------------------------------------------------
__global__ __launch_bounds__(1024) void out_proj(
    const unsigned short* __restrict__ tmp, const float* __restrict__ Wo,
    const float* __restrict__ bo, float* __restrict__ out)
{
    __shared__ __align__(16) short As[2][32 * 256];   // 2 x 16 KB

    const int tid  = threadIdx.x;
    const int lane = tid & 63, w = tid >> 6;
    const int l15  = lane & 15, l4 = lane >> 4;
    const int arow = tid >> 5, ak = (tid & 31) * 8;

    const int n = w * 16 + l15;               // lane's weight row
    short8 breg[8];
#pragma unroll
    for (int ks = 0; ks < 8; ++ks) {
        const float* s = &Wo[(size_t)n * K + ks * 32 + l4 * 8];
        breg[ks] = cvt8(*reinterpret_cast<const float4*>(s),
                        *reinterpret_cast<const float4*>(s + 4));
    }
    const int nbase = w * 16 + l4 * 4;        // output n-range after swap
    const float4 bias4 = *reinterpret_cast<const float4*>(&bo[nbase]);

    int t = blockIdx.x;
    short8 sa;
    auto lda = [&](int tt) {
        sa = *reinterpret_cast<const short8*>(&tmp[(size_t)(tt * 32 + arow) * K + ak]);
    };
    lda(t);
    lds_st16s(As[0], arow, 256, ak, sa);
    __syncthreads();
    int cur = 0;
    for (; t < NTILES; t += 256) {
        const bool more = (t + 256 < NTILES);
        if (more) lda(t + 256);

        f32x4 acc0 = {0.f, 0.f, 0.f, 0.f}, acc1 = {0.f, 0.f, 0.f, 0.f};
#pragma unroll
        for (int ks = 0; ks < 8; ++ks) {
            const int kc = ks * 32 + l4 * 8;
            const short8 a0 = lds_ld16s(As[cur], l15, 256, kc);
            const short8 a1 = lds_ld16s(As[cur], 16 + l15, 256, kc);
            acc0 = __builtin_amdgcn_mfma_f32_16x16x32_bf16(breg[ks], a0, acc0, 0, 0, 0);
            acc1 = __builtin_amdgcn_mfma_f32_16x16x32_bf16(breg[ks], a1, acc1, 0, 0, 0);
        }
        const int m0 = t * 32;
        {
            const int m = m0 + l15;
            float4 pv;
            pv.x = acc0[0] + bias4.x; pv.y = acc0[1] + bias4.y;
            pv.z = acc0[2] + bias4.z; pv.w = acc0[3] + bias4.w;
            *reinterpret_cast<float4*>(&out[(size_t)m * K + nbase]) = pv;
        }
        {
            const int m = m0 + 16 + l15;
            float4 pv;
            pv.x = acc1[0] + bias4.x; pv.y = acc1[1] + bias4.y;
            pv.z = acc1[2] + bias4.z; pv.w = acc1[3] + bias4.w;
            *reinterpret_cast<float4*>(&out[(size_t)m * K + nbase]) = pv;
        }
        if (more) lds_st16s(As[cur ^ 1], arow, 256, ak, sa);
        softbar();
        cur ^= 1;
    }
}

// ---------------------------------------------------------------------------
extern "C" void kernel_launch(void* const* d_in, const int* in_sizes, int n_in,
                              void* d_out, int out_size, void* d_ws, size_t ws_size,
                              hipStream_t stream)
{
    const float* hidden = (const float*)d_in[0];
    const float* enc    = (const float*)d_in[1];
    const float* refp   = (const float*)d_in[2];
    const float* W_off  = (const float*)d_in[4];
    const float* b_off  = (const float*)d_in[5];
    const float* W_attn = (const float*)d_in[6];
    const float* b_attn = (const float*)d_in[7];
    const float* W_val  = (const float*)d_in[8];
    const float* b_val  = (const float*)d_in[9];
    const float* W_out  = (const float*)d_in[10];
    const float* b_out  = (const float*)d_in[11];
    float* out = (float*)d_out;

    // workspace (u16 elements): vflat | proj | tmp
    unsigned short* vflat = (unsigned short*)d_ws;     // 10,240,000
    unsigned short* proj  = vflat + (size_t)10240000;  //  3,840,000
    unsigned short* tmp   = proj + (size_t)3840000;    // 10,240,000

    // 1) value proj (143 blocks) + off/attn proj (113 blocks), 64-row tiles
    stage1<<<256, 1024, 0, stream>>>(
        enc, W_val, b_val, vflat, hidden, W_off, W_attn, b_off, b_attn, proj);

    // 2) bilinear sampling + softmax aggregation -> tmp bf16 [M][256]
    sample_agg<<<5000, 256, 0, stream>>>(vflat, proj, refp, tmp);

    // 3) out projection (reg-B persistent, A dbuf, softbar) -> f32
    out_proj<<<256, 1024, 0, stream>>>(tmp, W_out, b_out, out);
}

// Round 22
// 72.116 us; speedup vs baseline: 1.0192x; 1.0192x over previous
//
#include <hip/hip_runtime.h>

constexpr int HH = 100;
constexpr int WW = 100;
constexpr int NH = 8;
constexpr int NP = 4;
constexpr int B  = 4;
constexpr int Q  = HH * WW;   // 10000
constexpr int S  = Q;
constexpr int K  = 256;
constexpr int DH = 32;
constexpr int M  = B * Q;     // 40000
constexpr int NTILES = M / 32; // 1250

typedef __attribute__((ext_vector_type(8))) short short8;
typedef __attribute__((ext_vector_type(4))) float f32x4;

struct __align__(8) ushort4p { unsigned short x, y, z, w; };

__device__ inline unsigned short f2bf(float f) {
    unsigned u = __builtin_bit_cast(unsigned, f);
    u += 0x7fffu + ((u >> 16) & 1u);          // RNE
    return (unsigned short)(u >> 16);
}
__device__ inline float bf2f(unsigned short h) {
    return __builtin_bit_cast(float, ((unsigned)h) << 16);
}
__device__ inline unsigned short f2h(float f) {
    _Float16 h = (_Float16)f;
    return __builtin_bit_cast(unsigned short, h);
}
__device__ inline float h2f(unsigned short u) {
    return (float)__builtin_bit_cast(_Float16, u);
}

// Non-draining barrier: waits LDS ops only; global stores/loads stay in flight.
__device__ inline void softbar() {
    asm volatile("s_waitcnt lgkmcnt(0)" ::: "memory");
    __builtin_amdgcn_s_barrier();
}

// LDS bf16 tile helpers (16B-chunk XOR swizzle: chunk ^= row&7).
__device__ inline void lds_st16s(short* base, int row, int stride, int kcol, short8 v) {
    *reinterpret_cast<short8*>(&base[row * stride + (kcol ^ ((row & 7) << 3))]) = v;
}
__device__ inline short8 lds_ld16s(const short* base, int row, int stride, int kcol) {
    return *reinterpret_cast<const short8*>(&base[row * stride + (kcol ^ ((row & 7) << 3))]);
}

__device__ inline short8 cvt8(float4 a, float4 b) {
    short8 r;
    r[0] = (short)f2bf(a.x); r[1] = (short)f2bf(a.y);
    r[2] = (short)f2bf(a.z); r[3] = (short)f2bf(a.w);
    r[4] = (short)f2bf(b.x); r[5] = (short)f2bf(b.y);
    r[6] = (short)f2bf(b.z); r[7] = (short)f2bf(b.w);
    return r;
}

// ---------------------------------------------------------------------------
// Stage 1 (R20 + T5 setprio): value proj + off/attn proj, heterogeneous
// persistent launch. 256 blocks x 1024 thr, B in VGPRs, A dbuf in LDS,
// 1-deep prefetch, softbar per tile, swapped-MFMA packed stores.
// s_setprio(1) around the MFMA cluster (waves drift via softbar -> role
// diversity -> scheduler favors MFMA-entering waves).
//   blocks 0..142   : enc @ W_val^T   -> vflat bf16
//   blocks 143..255 : hidden @ [W_off;W_attn]^T -> proj f16 [M][96]
// ---------------------------------------------------------------------------
__global__ __launch_bounds__(1024) void stage1(
    const float* __restrict__ enc, const float* __restrict__ Wval,
    const float* __restrict__ bval, unsigned short* __restrict__ vflat,
    const float* __restrict__ hidden, const float* __restrict__ Woff,
    const float* __restrict__ Wattn, const float* __restrict__ boff,
    const float* __restrict__ battn, unsigned short* __restrict__ proj)
{
    __shared__ __align__(16) short As[2][32 * 256];   // 2 x 16 KB

    const int tid  = threadIdx.x;
    const int lane = tid & 63, w = tid >> 6;
    const int l15  = lane & 15, l4 = lane >> 4;
    const int arow = tid >> 5, ak = (tid & 31) * 8;

    constexpr int NV = 143, NJ = 113;

    if (blockIdx.x < NV) {
        // ---------------- value projection ----------------
        const int n = w * 16 + l15;          // this lane's WEIGHT row
        short8 breg[8];
#pragma unroll
        for (int ks = 0; ks < 8; ++ks) {
            const float* s = &Wval[(size_t)n * K + ks * 32 + l4 * 8];
            breg[ks] = cvt8(*reinterpret_cast<const float4*>(s),
                            *reinterpret_cast<const float4*>(s + 4));
        }
        const int nbase = w * 16 + l4 * 4;
        const float4 bias4 = *reinterpret_cast<const float4*>(&bval[nbase]);
        const int h = w >> 1;                // nbase>>5, uniform per wave
        const int dd0 = nbase & 31;

        int t = blockIdx.x;
        float4 fa0, fa1;
        auto lda = [&](int tt) {
            const float* s = &enc[(size_t)(tt * 32 + arow) * K + ak];
            fa0 = *reinterpret_cast<const float4*>(s);
            fa1 = *reinterpret_cast<const float4*>(s + 4);
        };
        lda(t);
        lds_st16s(As[0], arow, 256, ak, cvt8(fa0, fa1));
        __syncthreads();
        int cur = 0;
        for (; t < NTILES; t += NV) {
            const bool more = (t + NV < NTILES);
            if (more) lda(t + NV);            // overlaps MFMA below

            f32x4 acc0 = {0.f, 0.f, 0.f, 0.f}, acc1 = {0.f, 0.f, 0.f, 0.f};
            __builtin_amdgcn_s_setprio(1);
#pragma unroll
            for (int ks = 0; ks < 8; ++ks) {
                const int kc = ks * 32 + l4 * 8;
                const short8 a0 = lds_ld16s(As[cur], l15, 256, kc);
                const short8 a1 = lds_ld16s(As[cur], 16 + l15, 256, kc);
                acc0 = __builtin_amdgcn_mfma_f32_16x16x32_bf16(breg[ks], a0, acc0, 0, 0, 0);
                acc1 = __builtin_amdgcn_mfma_f32_16x16x32_bf16(breg[ks], a1, acc1, 0, 0, 0);
            }
            __builtin_amdgcn_s_setprio(0);
            const int m0 = t * 32;
            {
                const int m = m0 + l15;
                const int b_ = m / S, s_ = m - b_ * S;
                ushort4p pk;
                pk.x = f2bf(acc0[0] + bias4.x);
                pk.y = f2bf(acc0[1] + bias4.y);
                pk.z = f2bf(acc0[2] + bias4.z);
                pk.w = f2bf(acc0[3] + bias4.w);
                *reinterpret_cast<ushort4p*>(
                    &vflat[(((size_t)(b_ * NH + h)) * S + s_) * DH + dd0]) = pk;
            }
            {
                const int m = m0 + 16 + l15;
                const int b_ = m / S, s_ = m - b_ * S;
                ushort4p pk;
                pk.x = f2bf(acc1[0] + bias4.x);
                pk.y = f2bf(acc1[1] + bias4.y);
                pk.z = f2bf(acc1[2] + bias4.z);
                pk.w = f2bf(acc1[3] + bias4.w);
                *reinterpret_cast<ushort4p*>(
                    &vflat[(((size_t)(b_ * NH + h)) * S + s_) * DH + dd0]) = pk;
            }
            if (more) lds_st16s(As[cur ^ 1], arow, 256, ak, cvt8(fa0, fa1));
            softbar();
            cur ^= 1;
        }
    } else {
        // ---------------- off+attn projection ----------------
        const int nf = w >> 1, mh = w & 1;   // waves 0..11 compute
        const int n = nf * 16 + l15;         // lane's weight row (0..95, w<12)
        short8 breg[8];
        float4 bias4 = {0.f, 0.f, 0.f, 0.f};
        const int nbase = nf * 16 + l4 * 4;  // output n-range after swap
        if (w < 12) {
#pragma unroll
            for (int ks = 0; ks < 8; ++ks) {
                const float* s = (n < 64)
                    ? &Woff[(size_t)n * K + ks * 32 + l4 * 8]
                    : &Wattn[(size_t)(n - 64) * K + ks * 32 + l4 * 8];
                breg[ks] = cvt8(*reinterpret_cast<const float4*>(s),
                                *reinterpret_cast<const float4*>(s + 4));
            }
            bias4 = (nf < 4)
                ? *reinterpret_cast<const float4*>(&boff[nbase])
                : *reinterpret_cast<const float4*>(&battn[nbase - 64]);
        }

        int t = blockIdx.x - NV;
        float4 fa0, fa1;
        auto lda = [&](int tt) {
            const float* s = &hidden[(size_t)(tt * 32 + arow) * K + ak];
            fa0 = *reinterpret_cast<const float4*>(s);
            fa1 = *reinterpret_cast<const float4*>(s + 4);
        };
        lda(t);
        lds_st16s(As[0], arow, 256, ak, cvt8(fa0, fa1));
        __syncthreads();
        int cur = 0;
        for (; t < NTILES; t += NJ) {
            const bool more = (t + NJ < NTILES);
            if (more) lda(t + NJ);

            if (w < 12) {
                f32x4 acc = {0.f, 0.f, 0.f, 0.f};
                __builtin_amdgcn_s_setprio(1);
#pragma unroll
                for (int ks = 0; ks < 8; ++ks) {
                    const int kc = ks * 32 + l4 * 8;
                    const short8 a = lds_ld16s(As[cur], mh * 16 + l15, 256, kc);
                    acc = __builtin_amdgcn_mfma_f32_16x16x32_bf16(breg[ks], a, acc, 0, 0, 0);
                }
                __builtin_amdgcn_s_setprio(0);
                const int m = t * 32 + mh * 16 + l15;
                ushort4p pk;
                pk.x = f2h(acc[0] + bias4.x);
                pk.y = f2h(acc[1] + bias4.y);
                pk.z = f2h(acc[2] + bias4.z);
                pk.w = f2h(acc[3] + bias4.w);
                *reinterpret_cast<ushort4p*>(&proj[(size_t)m * 96 + nbase]) = pk;
            }
            if (more) lds_st16s(As[cur ^ 1], arow, 256, ak, cvt8(fa0, fa1));
            softbar();
            cur ^= 1;
        }
    }
}

// ---------------------------------------------------------------------------
// Kernel S: bilinear sampling + attention aggregation (R14 exact).
// 4 lanes per (b,h,q) group; lane owns 8 d-elements (16B gathers).
// 64 groups per 256-thread block; 5000 blocks, XCD-swizzled.
// ---------------------------------------------------------------------------
__global__ __launch_bounds__(256) void sample_agg(
    const unsigned short* __restrict__ vflat,  // [B*NH][S][DH] bf16
    const unsigned short* __restrict__ proj,   // [M][96] f16
    const float* __restrict__ ref,             // [M][2]
    unsigned short* __restrict__ tmp)          // [M][256] bf16
{
    const int nblk = gridDim.x;                // 5000, %8 == 0
    const int cpx  = nblk >> 3;
    const int swz  = (blockIdx.x & 7) * cpx + (blockIdx.x >> 3);

    const int lg   = threadIdx.x >> 2;   // 0..63
    const int lane = threadIdx.x & 3;
    const int d0   = lane * 8;

    const int g  = swz * 64 + lg;
    const int q  = g % Q;
    const int bh = g / Q;
    const int b  = bh >> 3;
    const int h  = bh & 7;

    const size_t bq = (size_t)b * Q + q;
    const float refx = ref[bq * 2 + 0];
    const float refy = ref[bq * 2 + 1];
    const unsigned short* pr = proj + bq * 96;

    float l[NP];
#pragma unroll
    for (int p = 0; p < NP; ++p) l[p] = h2f(pr[64 + h * 4 + p]);
    const float mx = fmaxf(fmaxf(l[0], l[1]), fmaxf(l[2], l[3]));
    float e[NP];
    float esum = 0.f;
#pragma unroll
    for (int p = 0; p < NP; ++p) { e[p] = __expf(l[p] - mx); esum += e[p]; }
    const float inv = 1.f / esum;

    const unsigned short* vbase = vflat + (size_t)bh * (S * DH);

    int   cidx[NP][4];
    float cw[NP][4];
#pragma unroll
    for (int p = 0; p < NP; ++p) {
        const float ox = h2f(pr[h * 8 + p * 2 + 0]);
        const float oy = h2f(pr[h * 8 + p * 2 + 1]);
        const float x = fmaf(refx, (float)WW, ox) - 0.5f;
        const float y = fmaf(refy, (float)HH, oy) - 0.5f;
        const float x0f = floorf(x), y0f = floorf(y);
        const float wx1 = x - x0f, wx0 = 1.f - wx1;
        const float wy1 = y - y0f, wy0 = 1.f - wy1;
        const int x0 = (int)x0f, y0 = (int)y0f;
        const bool vx0 = (x0 >= 0) && (x0 < WW);
        const bool vx1 = (x0 + 1 >= 0) && (x0 + 1 < WW);
        const bool vy0 = (y0 >= 0) && (y0 < HH);
        const bool vy1 = (y0 + 1 >= 0) && (y0 + 1 < HH);
        const int xi0 = min(max(x0, 0), WW - 1);
        const int xi1 = min(max(x0 + 1, 0), WW - 1);
        const int yi0 = min(max(y0, 0), HH - 1);
        const int yi1 = min(max(y0 + 1, 0), HH - 1);
        const float ap = e[p] * inv;
        cw[p][0] = ap * wx0 * wy0 * ((vx0 && vy0) ? 1.f : 0.f);
        cw[p][1] = ap * wx1 * wy0 * ((vx1 && vy0) ? 1.f : 0.f);
        cw[p][2] = ap * wx0 * wy1 * ((vx0 && vy1) ? 1.f : 0.f);
        cw[p][3] = ap * wx1 * wy1 * ((vx1 && vy1) ? 1.f : 0.f);
        cidx[p][0] = (yi0 * WW + xi0) * DH + d0;
        cidx[p][1] = (yi0 * WW + xi1) * DH + d0;
        cidx[p][2] = (yi1 * WW + xi0) * DH + d0;
        cidx[p][3] = (yi1 * WW + xi1) * DH + d0;
    }

    float o[8];
#pragma unroll
    for (int j = 0; j < 8; ++j) o[j] = 0.f;
#pragma unroll
    for (int p = 0; p < NP; ++p) {
#pragma unroll
        for (int c = 0; c < 4; ++c) {
            const short8 v = *reinterpret_cast<const short8*>(&vbase[cidx[p][c]]);
            const float wgt = cw[p][c];
#pragma unroll
            for (int j = 0; j < 8; ++j)
                o[j] = fmaf(wgt, bf2f((unsigned short)v[j]), o[j]);
        }
    }

    short8 ov;
#pragma unroll
    for (int j = 0; j < 8; ++j) ov[j] = (short)f2bf(o[j]);
    *reinterpret_cast<short8*>(&tmp[bq * 256 + h * 32 + d0]) = ov;
}

// ---------------------------------------------------------------------------
// Kernel O: out projection (R20 + T5 setprio): 256 blocks x 1024 thr,
// W in VGPRs, A dbuf in LDS, 1-deep prefetch, softbar, packed f32x4 stores.
// ---------------------------------------------------------------------------
__global__ __launch_bounds__(1024) void out_proj(
    const unsigned short* __restrict__ tmp, const float* __restrict__ Wo,
    const float* __restrict__ bo, float* __restrict__ out)
{
    __shared__ __align__(16) short As[2][32 * 256];   // 2 x 16 KB

    const int tid  = threadIdx.x;
    const int lane = tid & 63, w = tid >> 6;
    const int l15  = lane & 15, l4 = lane >> 4;
    const int arow = tid >> 5, ak = (tid & 31) * 8;

    const int n = w * 16 + l15;               // lane's weight row
    short8 breg[8];
#pragma unroll
    for (int ks = 0; ks < 8; ++ks) {
        const float* s = &Wo[(size_t)n * K + ks * 32 + l4 * 8];
        breg[ks] = cvt8(*reinterpret_cast<const float4*>(s),
                        *reinterpret_cast<const float4*>(s + 4));
    }
    const int nbase = w * 16 + l4 * 4;        // output n-range after swap
    const float4 bias4 = *reinterpret_cast<const float4*>(&bo[nbase]);

    int t = blockIdx.x;
    short8 sa;
    auto lda = [&](int tt) {
        sa = *reinterpret_cast<const short8*>(&tmp[(size_t)(tt * 32 + arow) * K + ak]);
    };
    lda(t);
    lds_st16s(As[0], arow, 256, ak, sa);
    __syncthreads();
    int cur = 0;
    for (; t < NTILES; t += 256) {
        const bool more = (t + 256 < NTILES);
        if (more) lda(t + 256);

        f32x4 acc0 = {0.f, 0.f, 0.f, 0.f}, acc1 = {0.f, 0.f, 0.f, 0.f};
        __builtin_amdgcn_s_setprio(1);
#pragma unroll
        for (int ks = 0; ks < 8; ++ks) {
            const int kc = ks * 32 + l4 * 8;
            const short8 a0 = lds_ld16s(As[cur], l15, 256, kc);
            const short8 a1 = lds_ld16s(As[cur], 16 + l15, 256, kc);
            acc0 = __builtin_amdgcn_mfma_f32_16x16x32_bf16(breg[ks], a0, acc0, 0, 0, 0);
            acc1 = __builtin_amdgcn_mfma_f32_16x16x32_bf16(breg[ks], a1, acc1, 0, 0, 0);
        }
        __builtin_amdgcn_s_setprio(0);
        const int m0 = t * 32;
        {
            const int m = m0 + l15;
            float4 pv;
            pv.x = acc0[0] + bias4.x; pv.y = acc0[1] + bias4.y;
            pv.z = acc0[2] + bias4.z; pv.w = acc0[3] + bias4.w;
            *reinterpret_cast<float4*>(&out[(size_t)m * K + nbase]) = pv;
        }
        {
            const int m = m0 + 16 + l15;
            float4 pv;
            pv.x = acc1[0] + bias4.x; pv.y = acc1[1] + bias4.y;
            pv.z = acc1[2] + bias4.z; pv.w = acc1[3] + bias4.w;
            *reinterpret_cast<float4*>(&out[(size_t)m * K + nbase]) = pv;
        }
        if (more) lds_st16s(As[cur ^ 1], arow, 256, ak, sa);
        softbar();
        cur ^= 1;
    }
}

// ---------------------------------------------------------------------------
extern "C" void kernel_launch(void* const* d_in, const int* in_sizes, int n_in,
                              void* d_out, int out_size, void* d_ws, size_t ws_size,
                              hipStream_t stream)
{
    const float* hidden = (const float*)d_in[0];
    const float* enc    = (const float*)d_in[1];
    const float* refp   = (const float*)d_in[2];
    const float* W_off  = (const float*)d_in[4];
    const float* b_off  = (const float*)d_in[5];
    const float* W_attn = (const float*)d_in[6];
    const float* b_attn = (const float*)d_in[7];
    const float* W_val  = (const float*)d_in[8];
    const float* b_val  = (const float*)d_in[9];
    const float* W_out  = (const float*)d_in[10];
    const float* b_out  = (const float*)d_in[11];
    float* out = (float*)d_out;

    // workspace (u16 elements): vflat | proj | tmp
    unsigned short* vflat = (unsigned short*)d_ws;     // 10,240,000
    unsigned short* proj  = vflat + (size_t)10240000;  //  3,840,000
    unsigned short* tmp   = proj + (size_t)3840000;    // 10,240,000

    // 1) value proj (143 blocks) + off/attn proj (113 blocks), reg-B persistent
    stage1<<<256, 1024, 0, stream>>>(
        enc, W_val, b_val, vflat, hidden, W_off, W_attn, b_off, b_attn, proj);

    // 2) bilinear sampling + softmax aggregation -> tmp bf16 [M][256]
    sample_agg<<<5000, 256, 0, stream>>>(vflat, proj, refp, tmp);

    // 3) out projection (reg-B persistent, A dbuf, softbar, setprio) -> f32
    out_proj<<<256, 1024, 0, stream>>>(tmp, W_out, b_out, out);
}

// Round 23
// 71.785 us; speedup vs baseline: 1.0239x; 1.0046x over previous
//
#include <hip/hip_runtime.h>

constexpr int HH = 100;
constexpr int WW = 100;
constexpr int NH = 8;
constexpr int NP = 4;
constexpr int B  = 4;
constexpr int Q  = HH * WW;   // 10000
constexpr int S  = Q;
constexpr int K  = 256;
constexpr int DH = 32;
constexpr int M  = B * Q;     // 40000
constexpr int NTILES = M / 32; // 1250

typedef __attribute__((ext_vector_type(8))) short short8;
typedef __attribute__((ext_vector_type(4))) float f32x4;

struct __align__(8) ushort4p { unsigned short x, y, z, w; };

__device__ inline unsigned short f2bf(float f) {
    unsigned u = __builtin_bit_cast(unsigned, f);
    u += 0x7fffu + ((u >> 16) & 1u);          // RNE
    return (unsigned short)(u >> 16);
}
__device__ inline float bf2f(unsigned short h) {
    return __builtin_bit_cast(float, ((unsigned)h) << 16);
}
__device__ inline unsigned short f2h(float f) {
    _Float16 h = (_Float16)f;
    return __builtin_bit_cast(unsigned short, h);
}
__device__ inline float h2f(unsigned short u) {
    return (float)__builtin_bit_cast(_Float16, u);
}

// Non-draining barrier: waits LDS ops only (cross-wave visibility of the
// ds_writes); outstanding global stores and prefetch loads stay in flight.
__device__ inline void softbar() {
    asm volatile("s_waitcnt lgkmcnt(0)" ::: "memory");
    __builtin_amdgcn_s_barrier();
}

// LDS bf16 tile helpers (16B-chunk XOR swizzle: chunk ^= row&7).
__device__ inline void lds_st16s(short* base, int row, int stride, int kcol, short8 v) {
    *reinterpret_cast<short8*>(&base[row * stride + (kcol ^ ((row & 7) << 3))]) = v;
}
__device__ inline short8 lds_ld16s(const short* base, int row, int stride, int kcol) {
    return *reinterpret_cast<const short8*>(&base[row * stride + (kcol ^ ((row & 7) << 3))]);
}

__device__ inline short8 cvt8(float4 a, float4 b) {
    short8 r;
    r[0] = (short)f2bf(a.x); r[1] = (short)f2bf(a.y);
    r[2] = (short)f2bf(a.z); r[3] = (short)f2bf(a.w);
    r[4] = (short)f2bf(b.x); r[5] = (short)f2bf(b.y);
    r[6] = (short)f2bf(b.z); r[7] = (short)f2bf(b.w);
    return r;
}

// ---------------------------------------------------------------------------
// Stage 1 (session champion, R20): value proj + off/attn proj, heterogeneous
// persistent launch. 256 blocks x 1024 thr, B in VGPRs, A dbuf in LDS,
// 1-deep prefetch, softbar per tile, swapped-MFMA packed stores.
//   blocks 0..142   : enc @ W_val^T   -> vflat bf16
//   blocks 143..255 : hidden @ [W_off;W_attn]^T -> proj f16 [M][96]
// ---------------------------------------------------------------------------
__global__ __launch_bounds__(1024) void stage1(
    const float* __restrict__ enc, const float* __restrict__ Wval,
    const float* __restrict__ bval, unsigned short* __restrict__ vflat,
    const float* __restrict__ hidden, const float* __restrict__ Woff,
    const float* __restrict__ Wattn, const float* __restrict__ boff,
    const float* __restrict__ battn, unsigned short* __restrict__ proj)
{
    __shared__ __align__(16) short As[2][32 * 256];   // 2 x 16 KB

    const int tid  = threadIdx.x;
    const int lane = tid & 63, w = tid >> 6;
    const int l15  = lane & 15, l4 = lane >> 4;
    const int arow = tid >> 5, ak = (tid & 31) * 8;

    constexpr int NV = 143, NJ = 113;

    if (blockIdx.x < NV) {
        // ---------------- value projection ----------------
        const int n = w * 16 + l15;          // this lane's WEIGHT row
        short8 breg[8];
#pragma unroll
        for (int ks = 0; ks < 8; ++ks) {
            const float* s = &Wval[(size_t)n * K + ks * 32 + l4 * 8];
            breg[ks] = cvt8(*reinterpret_cast<const float4*>(s),
                            *reinterpret_cast<const float4*>(s + 4));
        }
        const int nbase = w * 16 + l4 * 4;
        const float4 bias4 = *reinterpret_cast<const float4*>(&bval[nbase]);
        const int h = w >> 1;                // nbase>>5, uniform per wave
        const int dd0 = nbase & 31;

        int t = blockIdx.x;
        float4 fa0, fa1;
        auto lda = [&](int tt) {
            const float* s = &enc[(size_t)(tt * 32 + arow) * K + ak];
            fa0 = *reinterpret_cast<const float4*>(s);
            fa1 = *reinterpret_cast<const float4*>(s + 4);
        };
        lda(t);
        lds_st16s(As[0], arow, 256, ak, cvt8(fa0, fa1));
        __syncthreads();
        int cur = 0;
        for (; t < NTILES; t += NV) {
            const bool more = (t + NV < NTILES);
            if (more) lda(t + NV);            // overlaps MFMA below

            f32x4 acc0 = {0.f, 0.f, 0.f, 0.f}, acc1 = {0.f, 0.f, 0.f, 0.f};
#pragma unroll
            for (int ks = 0; ks < 8; ++ks) {
                const int kc = ks * 32 + l4 * 8;
                const short8 a0 = lds_ld16s(As[cur], l15, 256, kc);
                const short8 a1 = lds_ld16s(As[cur], 16 + l15, 256, kc);
                acc0 = __builtin_amdgcn_mfma_f32_16x16x32_bf16(breg[ks], a0, acc0, 0, 0, 0);
                acc1 = __builtin_amdgcn_mfma_f32_16x16x32_bf16(breg[ks], a1, acc1, 0, 0, 0);
            }
            const int m0 = t * 32;
            {
                const int m = m0 + l15;
                const int b_ = m / S, s_ = m - b_ * S;
                ushort4p pk;
                pk.x = f2bf(acc0[0] + bias4.x);
                pk.y = f2bf(acc0[1] + bias4.y);
                pk.z = f2bf(acc0[2] + bias4.z);
                pk.w = f2bf(acc0[3] + bias4.w);
                *reinterpret_cast<ushort4p*>(
                    &vflat[(((size_t)(b_ * NH + h)) * S + s_) * DH + dd0]) = pk;
            }
            {
                const int m = m0 + 16 + l15;
                const int b_ = m / S, s_ = m - b_ * S;
                ushort4p pk;
                pk.x = f2bf(acc1[0] + bias4.x);
                pk.y = f2bf(acc1[1] + bias4.y);
                pk.z = f2bf(acc1[2] + bias4.z);
                pk.w = f2bf(acc1[3] + bias4.w);
                *reinterpret_cast<ushort4p*>(
                    &vflat[(((size_t)(b_ * NH + h)) * S + s_) * DH + dd0]) = pk;
            }
            if (more) lds_st16s(As[cur ^ 1], arow, 256, ak, cvt8(fa0, fa1));
            softbar();
            cur ^= 1;
        }
    } else {
        // ---------------- off+attn projection ----------------
        const int nf = w >> 1, mh = w & 1;   // waves 0..11 compute
        const int n = nf * 16 + l15;         // lane's weight row (0..95, w<12)
        short8 breg[8];
        float4 bias4 = {0.f, 0.f, 0.f, 0.f};
        const int nbase = nf * 16 + l4 * 4;  // output n-range after swap
        if (w < 12) {
#pragma unroll
            for (int ks = 0; ks < 8; ++ks) {
                const float* s = (n < 64)
                    ? &Woff[(size_t)n * K + ks * 32 + l4 * 8]
                    : &Wattn[(size_t)(n - 64) * K + ks * 32 + l4 * 8];
                breg[ks] = cvt8(*reinterpret_cast<const float4*>(s),
                                *reinterpret_cast<const float4*>(s + 4));
            }
            bias4 = (nf < 4)
                ? *reinterpret_cast<const float4*>(&boff[nbase])
                : *reinterpret_cast<const float4*>(&battn[nbase - 64]);
        }

        int t = blockIdx.x - NV;
        float4 fa0, fa1;
        auto lda = [&](int tt) {
            const float* s = &hidden[(size_t)(tt * 32 + arow) * K + ak];
            fa0 = *reinterpret_cast<const float4*>(s);
            fa1 = *reinterpret_cast<const float4*>(s + 4);
        };
        lda(t);
        lds_st16s(As[0], arow, 256, ak, cvt8(fa0, fa1));
        __syncthreads();
        int cur = 0;
        for (; t < NTILES; t += NJ) {
            const bool more = (t + NJ < NTILES);
            if (more) lda(t + NJ);

            if (w < 12) {
                f32x4 acc = {0.f, 0.f, 0.f, 0.f};
#pragma unroll
                for (int ks = 0; ks < 8; ++ks) {
                    const int kc = ks * 32 + l4 * 8;
                    const short8 a = lds_ld16s(As[cur], mh * 16 + l15, 256, kc);
                    acc = __builtin_amdgcn_mfma_f32_16x16x32_bf16(breg[ks], a, acc, 0, 0, 0);
                }
                const int m = t * 32 + mh * 16 + l15;
                ushort4p pk;
                pk.x = f2h(acc[0] + bias4.x);
                pk.y = f2h(acc[1] + bias4.y);
                pk.z = f2h(acc[2] + bias4.z);
                pk.w = f2h(acc[3] + bias4.w);
                *reinterpret_cast<ushort4p*>(&proj[(size_t)m * 96 + nbase]) = pk;
            }
            if (more) lds_st16s(As[cur ^ 1], arow, 256, ak, cvt8(fa0, fa1));
            softbar();
            cur ^= 1;
        }
    }
}

// ---------------------------------------------------------------------------
// Kernel S: bilinear sampling + attention aggregation.
// 4 lanes per (b,h,q) group; lane owns 8 d-elements (16B gathers).
// 64 groups per 256-thread block; 5000 blocks, XCD-swizzled so each XCD
// works on 4 contiguous (b,h) slices (2.56 MB, L2-resident).
// ---------------------------------------------------------------------------
__global__ __launch_bounds__(256) void sample_agg(
    const unsigned short* __restrict__ vflat,  // [B*NH][S][DH] bf16
    const unsigned short* __restrict__ proj,   // [M][96] f16
    const float* __restrict__ ref,             // [M][2]
    unsigned short* __restrict__ tmp)          // [M][256] bf16
{
    const int nblk = gridDim.x;                // 5000, %8 == 0
    const int cpx  = nblk >> 3;
    const int swz  = (blockIdx.x & 7) * cpx + (blockIdx.x >> 3);

    const int lg   = threadIdx.x >> 2;   // 0..63
    const int lane = threadIdx.x & 3;
    const int d0   = lane * 8;

    const int g  = swz * 64 + lg;
    const int q  = g % Q;
    const int bh = g / Q;
    const int b  = bh >> 3;
    const int h  = bh & 7;

    const size_t bq = (size_t)b * Q + q;
    const float refx = ref[bq * 2 + 0];
    const float refy = ref[bq * 2 + 1];
    const unsigned short* pr = proj + bq * 96;

    float l[NP];
#pragma unroll
    for (int p = 0; p < NP; ++p) l[p] = h2f(pr[64 + h * 4 + p]);
    const float mx = fmaxf(fmaxf(l[0], l[1]), fmaxf(l[2], l[3]));
    float e[NP];
    float esum = 0.f;
#pragma unroll
    for (int p = 0; p < NP; ++p) { e[p] = __expf(l[p] - mx); esum += e[p]; }
    const float inv = 1.f / esum;

    const unsigned short* vbase = vflat + (size_t)bh * (S * DH);

    int   cidx[NP][4];
    float cw[NP][4];
#pragma unroll
    for (int p = 0; p < NP; ++p) {
        const float ox = h2f(pr[h * 8 + p * 2 + 0]);
        const float oy = h2f(pr[h * 8 + p * 2 + 1]);
        const float x = fmaf(refx, (float)WW, ox) - 0.5f;
        const float y = fmaf(refy, (float)HH, oy) - 0.5f;
        const float x0f = floorf(x), y0f = floorf(y);
        const float wx1 = x - x0f, wx0 = 1.f - wx1;
        const float wy1 = y - y0f, wy0 = 1.f - wy1;
        const int x0 = (int)x0f, y0 = (int)y0f;
        const bool vx0 = (x0 >= 0) && (x0 < WW);
        const bool vx1 = (x0 + 1 >= 0) && (x0 + 1 < WW);
        const bool vy0 = (y0 >= 0) && (y0 < HH);
        const bool vy1 = (y0 + 1 >= 0) && (y0 + 1 < HH);
        const int xi0 = min(max(x0, 0), WW - 1);
        const int xi1 = min(max(x0 + 1, 0), WW - 1);
        const int yi0 = min(max(y0, 0), HH - 1);
        const int yi1 = min(max(y0 + 1, 0), HH - 1);
        const float ap = e[p] * inv;
        cw[p][0] = ap * wx0 * wy0 * ((vx0 && vy0) ? 1.f : 0.f);
        cw[p][1] = ap * wx1 * wy0 * ((vx1 && vy0) ? 1.f : 0.f);
        cw[p][2] = ap * wx0 * wy1 * ((vx0 && vy1) ? 1.f : 0.f);
        cw[p][3] = ap * wx1 * wy1 * ((vx1 && vy1) ? 1.f : 0.f);
        cidx[p][0] = (yi0 * WW + xi0) * DH + d0;
        cidx[p][1] = (yi0 * WW + xi1) * DH + d0;
        cidx[p][2] = (yi1 * WW + xi0) * DH + d0;
        cidx[p][3] = (yi1 * WW + xi1) * DH + d0;
    }

    float o[8];
#pragma unroll
    for (int j = 0; j < 8; ++j) o[j] = 0.f;
#pragma unroll
    for (int p = 0; p < NP; ++p) {
#pragma unroll
        for (int c = 0; c < 4; ++c) {
            const short8 v = *reinterpret_cast<const short8*>(&vbase[cidx[p][c]]);
            const float wgt = cw[p][c];
#pragma unroll
            for (int j = 0; j < 8; ++j)
                o[j] = fmaf(wgt, bf2f((unsigned short)v[j]), o[j]);
        }
    }

    short8 ov;
#pragma unroll
    for (int j = 0; j < 8; ++j) ov[j] = (short)f2bf(o[j]);
    *reinterpret_cast<short8*>(&tmp[bq * 256 + h * 32 + d0]) = ov;
}

// ---------------------------------------------------------------------------
// Kernel O: out projection (session champion, R20): 256 blocks x 1024 thr,
// W in VGPRs, A dbuf in LDS, 1-deep prefetch, softbar, swapped-MFMA f32x4
// packed stores.
// ---------------------------------------------------------------------------
__global__ __launch_bounds__(1024) void out_proj(
    const unsigned short* __restrict__ tmp, const float* __restrict__ Wo,
    const float* __restrict__ bo, float* __restrict__ out)
{
    __shared__ __align__(16) short As[2][32 * 256];   // 2 x 16 KB

    const int tid  = threadIdx.x;
    const int lane = tid & 63, w = tid >> 6;
    const int l15  = lane & 15, l4 = lane >> 4;
    const int arow = tid >> 5, ak = (tid & 31) * 8;

    const int n = w * 16 + l15;               // lane's weight row
    short8 breg[8];
#pragma unroll
    for (int ks = 0; ks < 8; ++ks) {
        const float* s = &Wo[(size_t)n * K + ks * 32 + l4 * 8];
        breg[ks] = cvt8(*reinterpret_cast<const float4*>(s),
                        *reinterpret_cast<const float4*>(s + 4));
    }
    const int nbase = w * 16 + l4 * 4;        // output n-range after swap
    const float4 bias4 = *reinterpret_cast<const float4*>(&bo[nbase]);

    int t = blockIdx.x;
    short8 sa;
    auto lda = [&](int tt) {
        sa = *reinterpret_cast<const short8*>(&tmp[(size_t)(tt * 32 + arow) * K + ak]);
    };
    lda(t);
    lds_st16s(As[0], arow, 256, ak, sa);
    __syncthreads();
    int cur = 0;
    for (; t < NTILES; t += 256) {
        const bool more = (t + 256 < NTILES);
        if (more) lda(t + 256);

        f32x4 acc0 = {0.f, 0.f, 0.f, 0.f}, acc1 = {0.f, 0.f, 0.f, 0.f};
#pragma unroll
        for (int ks = 0; ks < 8; ++ks) {
            const int kc = ks * 32 + l4 * 8;
            const short8 a0 = lds_ld16s(As[cur], l15, 256, kc);
            const short8 a1 = lds_ld16s(As[cur], 16 + l15, 256, kc);
            acc0 = __builtin_amdgcn_mfma_f32_16x16x32_bf16(breg[ks], a0, acc0, 0, 0, 0);
            acc1 = __builtin_amdgcn_mfma_f32_16x16x32_bf16(breg[ks], a1, acc1, 0, 0, 0);
        }
        const int m0 = t * 32;
        {
            const int m = m0 + l15;
            float4 pv;
            pv.x = acc0[0] + bias4.x; pv.y = acc0[1] + bias4.y;
            pv.z = acc0[2] + bias4.z; pv.w = acc0[3] + bias4.w;
            *reinterpret_cast<float4*>(&out[(size_t)m * K + nbase]) = pv;
        }
        {
            const int m = m0 + 16 + l15;
            float4 pv;
            pv.x = acc1[0] + bias4.x; pv.y = acc1[1] + bias4.y;
            pv.z = acc1[2] + bias4.z; pv.w = acc1[3] + bias4.w;
            *reinterpret_cast<float4*>(&out[(size_t)m * K + nbase]) = pv;
        }
        if (more) lds_st16s(As[cur ^ 1], arow, 256, ak, sa);
        softbar();
        cur ^= 1;
    }
}

// ---------------------------------------------------------------------------
extern "C" void kernel_launch(void* const* d_in, const int* in_sizes, int n_in,
                              void* d_out, int out_size, void* d_ws, size_t ws_size,
                              hipStream_t stream)
{
    const float* hidden = (const float*)d_in[0];
    const float* enc    = (const float*)d_in[1];
    const float* refp   = (const float*)d_in[2];
    const float* W_off  = (const float*)d_in[4];
    const float* b_off  = (const float*)d_in[5];
    const float* W_attn = (const float*)d_in[6];
    const float* b_attn = (const float*)d_in[7];
    const float* W_val  = (const float*)d_in[8];
    const float* b_val  = (const float*)d_in[9];
    const float* W_out  = (const float*)d_in[10];
    const float* b_out  = (const float*)d_in[11];
    float* out = (float*)d_out;

    // workspace (u16 elements): vflat | proj | tmp
    unsigned short* vflat = (unsigned short*)d_ws;     // 10,240,000
    unsigned short* proj  = vflat + (size_t)10240000;  //  3,840,000
    unsigned short* tmp   = proj + (size_t)3840000;    // 10,240,000

    // 1) value proj (143 blocks) + off/attn proj (113 blocks), reg-B persistent
    stage1<<<256, 1024, 0, stream>>>(
        enc, W_val, b_val, vflat, hidden, W_off, W_attn, b_off, b_attn, proj);

    // 2) bilinear sampling + softmax aggregation -> tmp bf16 [M][256]
    sample_agg<<<5000, 256, 0, stream>>>(vflat, proj, refp, tmp);

    // 3) out projection (reg-B persistent, A dbuf, softbar) -> f32
    out_proj<<<256, 1024, 0, stream>>>(tmp, W_out, b_out, out);
}